// Round 1
// baseline (1664.339 us; speedup 1.0000x reference)
//
#include <hip/hip_runtime.h>
#include <math.h>

#define L 8
#define D 512
#define P 128
#define H 8
#define HD 64
#define B 2
#define NS 4
#define S 384
#define BS (B*S)                     // 768
#define XN (BS*D)                    // 393216
#define SS ((size_t)S*S)             // 147456
#define BHSS ((size_t)B*H*S*S)       // 2359296

// ---------------- init: x = msa[:,0], coords = 0 ----------------
__global__ __launch_bounds__(256) void k_init(const float* __restrict__ msa,
                                              float* __restrict__ x,
                                              float* __restrict__ coords) {
    int idx = blockIdx.x * 256 + threadIdx.x;
    if (idx < XN) {
        int b = idx / (S * D);
        int rem = idx - b * (S * D);
        x[idx] = msa[(size_t)b * NS * S * D + rem];
    }
    if (idx < B * S * 3) coords[idx] = 0.f;
}

// ---------------- pair bias: bias[l,b,h,i,j] = sum_p pair[b,i,j,p]*Wpb[l,p,h] + bpb[l,h]
// one block: (b, i, 64-wide j tile), all nl*H (l,h) outputs
__global__ __launch_bounds__(256) void k_bias(const float* __restrict__ pair,
                                              const float* __restrict__ Wpb,
                                              const float* __restrict__ bpb,
                                              float* __restrict__ bias,
                                              int l0, int nl) {
    __shared__ float ps[64][132];   // 64 j rows x 128 p (pad to 132 for b128 reads)
    const int t = threadIdx.x;
    const int j0 = blockIdx.x * 64;
    const int i = blockIdx.y;
    const int b = blockIdx.z;

    const float* pb = pair + (((size_t)b * S + i) * S + j0) * P;
    #pragma unroll
    for (int m = 0; m < 32; m++) {
        int f = t + m * 256;                  // 8192 floats
        ps[f >> 7][f & 127] = pb[f];
    }
    __syncthreads();

    const int wv = t >> 6, lane = t & 63;
    const int nlh = nl * H;
    for (int ch = wv; ch * 4 < nlh; ch += 4) {
        const int lh0 = ch * 4;
        const int l = lh0 >> 3, h0 = lh0 & 7;
        const float* wb = Wpb + (size_t)(l0 + l) * P * H + h0;
        float a0 = 0.f, a1 = 0.f, a2 = 0.f, a3 = 0.f;
        #pragma unroll
        for (int p4 = 0; p4 < 32; p4++) {
            float4 pv = *(const float4*)&ps[lane][p4 * 4];
            const float* w0 = wb + p4 * 32;   // (4*p4 + q)*8 + c
            a0 += pv.x * w0[0];  a1 += pv.x * w0[1];  a2 += pv.x * w0[2];  a3 += pv.x * w0[3];
            a0 += pv.y * w0[8];  a1 += pv.y * w0[9];  a2 += pv.y * w0[10]; a3 += pv.y * w0[11];
            a0 += pv.z * w0[16]; a1 += pv.z * w0[17]; a2 += pv.z * w0[18]; a3 += pv.z * w0[19];
            a0 += pv.w * w0[24]; a1 += pv.w * w0[25]; a2 += pv.w * w0[26]; a3 += pv.w * w0[27];
        }
        const float* bp = bpb + (size_t)(l0 + l) * H + h0;
        float* ob = bias + (((size_t)l * B + b) * H + h0) * SS + (size_t)i * S + j0 + lane;
        ob[0]      = a0 + bp[0];
        ob[SS]     = a1 + bp[1];
        ob[2 * SS] = a2 + bp[2];
        ob[3 * SS] = a3 + bp[3];
    }
}

// ---------------- fused QKV projection, outputs in (B,H,S,HD) layout ----------------
__global__ __launch_bounds__(256) void k_qkv(const float* __restrict__ x,
        const float* __restrict__ Wq, const float* __restrict__ Wk, const float* __restrict__ Wv,
        const float* __restrict__ bq, const float* __restrict__ bk, const float* __restrict__ bv,
        float* __restrict__ qT, float* __restrict__ kT, float* __restrict__ vT) {
    const float* W; const float* bias; float* out;
    if (blockIdx.z == 0)      { W = Wq; bias = bq; out = qT; }
    else if (blockIdx.z == 1) { W = Wk; bias = bk; out = kT; }
    else                      { W = Wv; bias = bv; out = vT; }

    __shared__ float Ast[16][68];   // [k][row]
    __shared__ float Ws[16][68];    // [k][col]
    const int tx = threadIdx.x, ty = threadIdx.y;
    const int t = ty * 16 + tx;
    const int row0 = blockIdx.y * 64, col0 = blockIdx.x * 64;
    float acc[4][4] = {};

    for (int kt = 0; kt < D; kt += 16) {
        #pragma unroll
        for (int m = 0; m < 4; m++) {
            int f = t + m * 256;
            int r = f >> 4, c = f & 15;
            Ast[c][r] = x[(size_t)(row0 + r) * D + kt + c];
        }
        #pragma unroll
        for (int m = 0; m < 4; m++) {
            int f = t + m * 256;
            int r = f >> 6, c = f & 63;
            Ws[r][c] = W[(size_t)(kt + r) * D + col0 + c];
        }
        __syncthreads();
        #pragma unroll
        for (int kk = 0; kk < 16; kk++) {
            float4 av = *(const float4*)&Ast[kk][ty * 4];
            float4 bv4 = *(const float4*)&Ws[kk][tx * 4];
            acc[0][0] += av.x * bv4.x; acc[0][1] += av.x * bv4.y; acc[0][2] += av.x * bv4.z; acc[0][3] += av.x * bv4.w;
            acc[1][0] += av.y * bv4.x; acc[1][1] += av.y * bv4.y; acc[1][2] += av.y * bv4.z; acc[1][3] += av.y * bv4.w;
            acc[2][0] += av.z * bv4.x; acc[2][1] += av.z * bv4.y; acc[2][2] += av.z * bv4.z; acc[2][3] += av.z * bv4.w;
            acc[3][0] += av.w * bv4.x; acc[3][1] += av.w * bv4.y; acc[3][2] += av.w * bv4.z; acc[3][3] += av.w * bv4.w;
        }
        __syncthreads();
    }
    #pragma unroll
    for (int ii = 0; ii < 4; ii++) {
        int r = row0 + ty * 4 + ii;
        int b = r / S, i = r - b * S;
        #pragma unroll
        for (int jj = 0; jj < 4; jj++) {
            int c = col0 + tx * 4 + jj;
            int h = c >> 6, d = c & 63;
            out[(((size_t)b * H + h) * S + i) * HD + d] = acc[ii][jj] + bias[c];
        }
    }
}

// ---------------- generic GEMM: C[M,N] = A[M,K] @ W[K,N] + bias  (MODE 1: relu, 2: +resid)
template <int MODE>
__global__ __launch_bounds__(256) void k_gemm(const float* __restrict__ A,
        const float* __restrict__ W, const float* __restrict__ bias,
        float* __restrict__ C, const float* __restrict__ resid, int N, int K) {
    __shared__ float Ast[16][68];
    __shared__ float Ws[16][68];
    const int tx = threadIdx.x, ty = threadIdx.y;
    const int t = ty * 16 + tx;
    const int row0 = blockIdx.y * 64, col0 = blockIdx.x * 64;
    float acc[4][4] = {};

    for (int kt = 0; kt < K; kt += 16) {
        #pragma unroll
        for (int m = 0; m < 4; m++) {
            int f = t + m * 256;
            int r = f >> 4, c = f & 15;
            Ast[c][r] = A[(size_t)(row0 + r) * K + kt + c];
        }
        #pragma unroll
        for (int m = 0; m < 4; m++) {
            int f = t + m * 256;
            int r = f >> 6, c = f & 63;
            Ws[r][c] = W[(size_t)(kt + r) * N + col0 + c];
        }
        __syncthreads();
        #pragma unroll
        for (int kk = 0; kk < 16; kk++) {
            float4 av = *(const float4*)&Ast[kk][ty * 4];
            float4 bv4 = *(const float4*)&Ws[kk][tx * 4];
            acc[0][0] += av.x * bv4.x; acc[0][1] += av.x * bv4.y; acc[0][2] += av.x * bv4.z; acc[0][3] += av.x * bv4.w;
            acc[1][0] += av.y * bv4.x; acc[1][1] += av.y * bv4.y; acc[1][2] += av.y * bv4.z; acc[1][3] += av.y * bv4.w;
            acc[2][0] += av.z * bv4.x; acc[2][1] += av.z * bv4.y; acc[2][2] += av.z * bv4.z; acc[2][3] += av.z * bv4.w;
            acc[3][0] += av.w * bv4.x; acc[3][1] += av.w * bv4.y; acc[3][2] += av.w * bv4.z; acc[3][3] += av.w * bv4.w;
        }
        __syncthreads();
    }
    #pragma unroll
    for (int ii = 0; ii < 4; ii++) {
        int r = row0 + ty * 4 + ii;
        #pragma unroll
        for (int jj = 0; jj < 4; jj++) {
            int c = col0 + tx * 4 + jj;
            float v = acc[ii][jj] + bias[c];
            if (MODE == 1) v = fmaxf(v, 0.f);
            if (MODE == 2) v += resid[(size_t)r * N + c];
            C[(size_t)r * N + c] = v;
        }
    }
}

// ---------------- fused attention: scores+bias -> softmax -> @V, per (b,h,16 q-rows)
__global__ __launch_bounds__(256) void k_attn(const float* __restrict__ qT,
        const float* __restrict__ kT, const float* __restrict__ vT,
        const float* __restrict__ biasL, float* __restrict__ ao) {
    __shared__ float qs[16][64];
    __shared__ float ks[64][68];
    __shared__ float sc[16][392];
    const int t = threadIdx.x;
    const int i0 = blockIdx.x * 16;
    const int h = blockIdx.y, b = blockIdx.z;
    const size_t baseQ = ((size_t)b * H + h) * S * HD;
    const float* qb = qT + baseQ;
    const float* kb = kT + baseQ;
    const float* vb = vT + baseQ;
    const float* bb = biasL + ((size_t)b * H + h) * SS + (size_t)i0 * S;

    #pragma unroll
    for (int m = 0; m < 4; m++) {
        int f = t + m * 256;
        qs[f >> 6][f & 63] = qb[(size_t)(i0 + (f >> 6)) * HD + (f & 63)];
    }
    const int i = t >> 4;
    const int j4 = (t & 15) * 4;

    for (int jt = 0; jt < S; jt += 64) {
        #pragma unroll
        for (int m = 0; m < 16; m++) {
            int f = t + m * 256;
            ks[f >> 6][f & 63] = kb[(size_t)(jt + (f >> 6)) * HD + (f & 63)];
        }
        __syncthreads();
        float s0 = 0.f, s1 = 0.f, s2 = 0.f, s3 = 0.f;
        #pragma unroll
        for (int d4 = 0; d4 < 64; d4 += 4) {
            float4 qv = *(const float4*)&qs[i][d4];
            float4 k0 = *(const float4*)&ks[j4 + 0][d4];
            float4 k1 = *(const float4*)&ks[j4 + 1][d4];
            float4 k2 = *(const float4*)&ks[j4 + 2][d4];
            float4 k3 = *(const float4*)&ks[j4 + 3][d4];
            s0 += qv.x * k0.x + qv.y * k0.y + qv.z * k0.z + qv.w * k0.w;
            s1 += qv.x * k1.x + qv.y * k1.y + qv.z * k1.z + qv.w * k1.w;
            s2 += qv.x * k2.x + qv.y * k2.y + qv.z * k2.z + qv.w * k2.w;
            s3 += qv.x * k3.x + qv.y * k3.y + qv.z * k3.z + qv.w * k3.w;
        }
        const float* bp = bb + (size_t)i * S + jt + j4;
        sc[i][jt + j4 + 0] = s0 * 0.125f + bp[0];
        sc[i][jt + j4 + 1] = s1 * 0.125f + bp[1];
        sc[i][jt + j4 + 2] = s2 * 0.125f + bp[2];
        sc[i][jt + j4 + 3] = s3 * 0.125f + bp[3];
        __syncthreads();
    }

    // softmax along j (16 threads per row, all in same wave group)
    const int sub = t & 15;
    float mx = -1e30f;
    for (int j = sub; j < S; j += 16) mx = fmaxf(mx, sc[i][j]);
    #pragma unroll
    for (int m = 1; m < 16; m <<= 1) mx = fmaxf(mx, __shfl_xor(mx, m));
    float sum = 0.f;
    for (int j = sub; j < S; j += 16) {
        float p = __expf(sc[i][j] - mx);
        sc[i][j] = p;
        sum += p;
    }
    #pragma unroll
    for (int m = 1; m < 16; m <<= 1) sum += __shfl_xor(sum, m);
    const float inv = 1.f / sum;
    for (int j = sub; j < S; j += 16) sc[i][j] *= inv;
    __syncthreads();

    // out = attn @ V
    const int d4 = (t & 15) * 4;
    float o0 = 0.f, o1 = 0.f, o2 = 0.f, o3 = 0.f;
    for (int jt = 0; jt < S; jt += 64) {
        #pragma unroll
        for (int m = 0; m < 16; m++) {
            int f = t + m * 256;
            ks[f >> 6][f & 63] = vb[(size_t)(jt + (f >> 6)) * HD + (f & 63)];
        }
        __syncthreads();
        #pragma unroll 8
        for (int jj = 0; jj < 64; jj++) {
            float a = sc[i][jt + jj];
            float4 vv = *(const float4*)&ks[jj][d4];
            o0 += a * vv.x; o1 += a * vv.y; o2 += a * vv.z; o3 += a * vv.w;
        }
        __syncthreads();
    }
    float* op = ao + ((size_t)(b * S + i0 + i)) * D + h * HD + d4;
    op[0] = o0; op[1] = o1; op[2] = o2; op[3] = o3;
}

// ---------------- coords update: coords += (relu_hidden @ Wb2 + bb2)[:, :3]
__global__ __launch_bounds__(256) void k_upd(const float* __restrict__ h1,
        const float* __restrict__ Wb2, const float* __restrict__ bb2,
        float* __restrict__ coords) {
    const int wv = threadIdx.x >> 6, lane = threadIdx.x & 63;
    const int row = blockIdx.x * 4 + wv;
    const float* hr = h1 + (size_t)row * D;
    float p0 = 0.f, p1 = 0.f, p2 = 0.f;
    #pragma unroll
    for (int m = 0; m < 8; m++) {
        int d = m * 64 + lane;
        float hv = hr[d];
        const float* w = Wb2 + (size_t)d * 6;
        p0 += hv * w[0]; p1 += hv * w[1]; p2 += hv * w[2];
    }
    #pragma unroll
    for (int m = 32; m; m >>= 1) {
        p0 += __shfl_xor(p0, m);
        p1 += __shfl_xor(p1, m);
        p2 += __shfl_xor(p2, m);
    }
    if (lane == 0) {
        coords[row * 3 + 0] += p0 + bb2[0];
        coords[row * 3 + 1] += p1 + bb2[1];
        coords[row * 3 + 2] += p2 + bb2[2];
    }
}

// ---------------- confidence + final output assembly ----------------
__global__ __launch_bounds__(256) void k_conf(const float* __restrict__ hc,
        const float* __restrict__ Wc2, const float* __restrict__ bc2,
        const float* __restrict__ coords, float* __restrict__ out) {
    const int wv = threadIdx.x >> 6, lane = threadIdx.x & 63;
    const int row = blockIdx.x * 4 + wv;
    const float* hr = hc + (size_t)row * 256;
    float p = 0.f;
    #pragma unroll
    for (int m = 0; m < 4; m++) p += hr[m * 64 + lane] * Wc2[m * 64 + lane];
    #pragma unroll
    for (int m = 32; m; m >>= 1) p += __shfl_xor(p, m);
    if (lane == 0) out[B * S * 3 + row] = 1.f / (1.f + __expf(-(p + bc2[0])));
    int ci = blockIdx.x * 12 + threadIdx.x;
    if (threadIdx.x < 12) out[ci] = coords[ci];
}

extern "C" void kernel_launch(void* const* d_in, const int* in_sizes, int n_in,
                              void* d_out, int out_size, void* d_ws, size_t ws_size,
                              hipStream_t stream) {
    const float* msa = (const float*)d_in[0];
    const float* pair = (const float*)d_in[1];
    const float* Wq = (const float*)d_in[2];
    const float* bq = (const float*)d_in[3];
    const float* Wk = (const float*)d_in[4];
    const float* bk = (const float*)d_in[5];
    const float* Wv = (const float*)d_in[6];
    const float* bv = (const float*)d_in[7];
    const float* Wpb = (const float*)d_in[8];
    const float* bpb = (const float*)d_in[9];
    const float* Wo = (const float*)d_in[10];
    const float* bo = (const float*)d_in[11];
    const float* Wb1 = (const float*)d_in[12];
    const float* bb1 = (const float*)d_in[13];
    const float* Wb2 = (const float*)d_in[14];
    const float* bb2 = (const float*)d_in[15];
    const float* Wc1 = (const float*)d_in[16];
    const float* bc1 = (const float*)d_in[17];
    const float* Wc2 = (const float*)d_in[18];
    const float* bc2 = (const float*)d_in[19];

    float* ws = (float*)d_ws;
    float* x      = ws;
    float* qT     = ws + (size_t)XN;
    float* kT     = ws + 2 * (size_t)XN;
    float* vT     = ws + 3 * (size_t)XN;
    float* ao     = ws + 4 * (size_t)XN;
    float* h1     = ws + 5 * (size_t)XN;
    float* coords = ws + 6 * (size_t)XN;
    float* biasb  = ws + 6 * (size_t)XN + 4096;

    const size_t needFull = ((size_t)6 * XN + 4096 + (size_t)L * BHSS) * sizeof(float);
    const bool full = ws_size >= needFull;   // all-layer bias precompute fits?

    k_init<<<dim3((XN + 255) / 256), 256, 0, stream>>>(msa, x, coords);
    if (full)
        k_bias<<<dim3(S / 64, S, B), 256, 0, stream>>>(pair, Wpb, bpb, biasb, 0, L);

    for (int l = 0; l < L; ++l) {
        if (!full)
            k_bias<<<dim3(S / 64, S, B), 256, 0, stream>>>(pair, Wpb, bpb, biasb, l, 1);
        k_qkv<<<dim3(D / 64, BS / 64, 3), dim3(16, 16), 0, stream>>>(x,
            Wq + (size_t)l * D * D, Wk + (size_t)l * D * D, Wv + (size_t)l * D * D,
            bq + l * D, bk + l * D, bv + l * D, qT, kT, vT);
        const float* bl = biasb + (full ? (size_t)l * BHSS : 0);
        k_attn<<<dim3(S / 16, H, B), 256, 0, stream>>>(qT, kT, vT, bl, ao);
        k_gemm<2><<<dim3(D / 64, BS / 64), dim3(16, 16), 0, stream>>>(ao,
            Wo + (size_t)l * D * D, bo + l * D, x, x, D, D);
        k_gemm<1><<<dim3(D / 64, BS / 64), dim3(16, 16), 0, stream>>>(x,
            Wb1, bb1, h1, nullptr, D, D);
        k_upd<<<BS / 4, 256, 0, stream>>>(h1, Wb2, bb2, coords);
    }

    k_gemm<1><<<dim3(256 / 64, BS / 64), dim3(16, 16), 0, stream>>>(x,
        Wc1, bc1, h1, nullptr, 256, D);
    k_conf<<<BS / 4, 256, 0, stream>>>(h1, Wc2, bc2, coords, (float*)d_out);
}

// Round 3
// 906.827 us; speedup vs baseline: 1.8353x; 1.8353x over previous
//
#include <hip/hip_runtime.h>
#include <math.h>

#define L 8
#define D 512
#define DD (D*D)
#define P 128
#define H 8
#define HD 64
#define B 2
#define NS 4
#define S 384
#define BS (B*S)                     // 768
#define XN (BS*D)                    // 393216
#define SS ((size_t)S*S)             // 147456
#define BHSS ((size_t)B*H*S*S)       // 2359296

typedef short bf16x8 __attribute__((ext_vector_type(8)));
typedef float f32x4 __attribute__((ext_vector_type(4)));

__device__ __forceinline__ unsigned short f2b(float f) {
    unsigned u = __float_as_uint(f);
    unsigned r = (u + 0x7FFF + ((u >> 16) & 1)) >> 16;
    return (unsigned short)r;
}
__device__ __forceinline__ float b2f(unsigned short u) {
    return __uint_as_float(((unsigned)u) << 16);
}

// ---------------- init: x = msa[:,0] (f32 + bf16), coords = 0 ----------------
__global__ __launch_bounds__(256) void k_init(const float* __restrict__ msa,
                                              float* __restrict__ x,
                                              unsigned short* __restrict__ xb,
                                              float* __restrict__ coords) {
    int idx = blockIdx.x * 256 + threadIdx.x;
    if (idx < XN) {
        int b = idx / (S * D);
        int rem = idx - b * (S * D);
        float v = msa[(size_t)b * NS * S * D + rem];
        x[idx] = v;
        xb[idx] = f2b(v);
    }
    if (idx < B * S * 3) coords[idx] = 0.f;
}

// ---------------- weight prep: transpose+convert to bf16 [N][K] ----------------
// z: 0-7 Wq[l], 8-15 Wk, 16-23 Wv, 24-31 Wo, 32 Wb1, 33 Wc1 (N=256)
__global__ __launch_bounds__(256) void k_prep(const float* __restrict__ Wq,
        const float* __restrict__ Wk, const float* __restrict__ Wv,
        const float* __restrict__ Wo, const float* __restrict__ Wb1,
        const float* __restrict__ Wc1, unsigned short* __restrict__ wt) {
    __shared__ float ts[64][65];
    const int z = blockIdx.z;
    const float* src; int N = 512;
    if (z < 8)       src = Wq + (size_t)z * DD;
    else if (z < 16) src = Wk + (size_t)(z - 8) * DD;
    else if (z < 24) src = Wv + (size_t)(z - 16) * DD;
    else if (z < 32) src = Wo + (size_t)(z - 24) * DD;
    else if (z == 32) src = Wb1;
    else { src = Wc1; N = 256; }
    unsigned short* dst = wt + (size_t)z * DD;

    const int n0 = blockIdx.x * 64, k0 = blockIdx.y * 64;
    if (n0 >= N) return;
    const int t = threadIdx.x;
    #pragma unroll
    for (int m = 0; m < 16; m++) {
        int f = t + m * 256;
        int r = f >> 6, c = f & 63;
        ts[r][c] = src[(size_t)(k0 + r) * N + n0 + c];
    }
    __syncthreads();
    #pragma unroll
    for (int m = 0; m < 4; m++) {
        int o4 = t + m * 256;
        int nr = o4 >> 4, k4 = o4 & 15;
        ushort4 pk;
        pk.x = f2b(ts[k4 * 4 + 0][nr]);
        pk.y = f2b(ts[k4 * 4 + 1][nr]);
        pk.z = f2b(ts[k4 * 4 + 2][nr]);
        pk.w = f2b(ts[k4 * 4 + 3][nr]);
        *(ushort4*)&dst[(size_t)(n0 + nr) * 512 + k0 + k4 * 4] = pk;
    }
}

// ---------------- pair bias via MFMA: bias[l,b,h,i,j] (bf16 out) ----------------
// block = (i, b); computes all 64 (l,h) x 384 j. A = W'[lh][k] (regs), B = pair[j][k]
__global__ __launch_bounds__(256) void k_biasm(const float* __restrict__ pair,
        const float* __restrict__ Wpb, const float* __restrict__ bpb,
        unsigned short* __restrict__ bias) {
    __shared__ unsigned short Ws[64][136];   // [lh][k]
    __shared__ unsigned short Ps[64][136];   // [j][k]
    const int t = threadIdx.x;
    const int lane = t & 63, w = t >> 6;
    const int i = blockIdx.x, b = blockIdx.y;

    #pragma unroll
    for (int m = 0; m < 32; m++) {
        int f = t + m * 256;
        int lh = f >> 7, k = f & 127;
        Ws[lh][k] = f2b(Wpb[(size_t)(lh >> 3) * (P * H) + k * 8 + (lh & 7)]);
    }
    __syncthreads();

    bf16x8 af[4][4];
    #pragma unroll
    for (int mi = 0; mi < 4; mi++)
        #pragma unroll
        for (int ks = 0; ks < 4; ks++)
            af[mi][ks] = *(const bf16x8*)&Ws[mi * 16 + (lane & 15)][ks * 32 + (lane >> 4) * 8];

    const float* prow = pair + ((size_t)b * S + i) * S * P;
    f32x4 zero; zero[0] = zero[1] = zero[2] = zero[3] = 0.f;

    for (int jt = 0; jt < 6; jt++) {
        __syncthreads();
        #pragma unroll
        for (int m = 0; m < 32; m++) {
            int f = t + m * 256;
            int r = f >> 7, c = f & 127;
            Ps[r][c] = f2b(prow[(size_t)(jt * 64 + r) * P + c]);
        }
        __syncthreads();
        f32x4 acc[4];
        #pragma unroll
        for (int mi = 0; mi < 4; mi++) acc[mi] = zero;
        #pragma unroll
        for (int ks = 0; ks < 4; ks++) {
            bf16x8 bv = *(const bf16x8*)&Ps[w * 16 + (lane & 15)][ks * 32 + (lane >> 4) * 8];
            #pragma unroll
            for (int mi = 0; mi < 4; mi++)
                acc[mi] = __builtin_amdgcn_mfma_f32_16x16x32_bf16(af[mi][ks], bv, acc[mi], 0, 0, 0);
        }
        const int j = jt * 64 + w * 16 + (lane & 15);
        #pragma unroll
        for (int mi = 0; mi < 4; mi++)
            #pragma unroll
            for (int reg = 0; reg < 4; reg++) {
                int lh = mi * 16 + (lane >> 4) * 4 + reg;
                float v = acc[mi][reg] + bpb[lh];
                size_t plane = ((size_t)(lh >> 3) * B + b) * H + (lh & 7);
                bias[plane * SS + (size_t)i * S + j] = f2b(v);
            }
    }
}

// ---------------- QKV MFMA GEMM, outputs f32 (B,H,S,HD) ----------------
__global__ __launch_bounds__(256) void k_qkvm(const unsigned short* __restrict__ xb,
        const unsigned short* __restrict__ wt,
        const float* __restrict__ bq, const float* __restrict__ bk, const float* __restrict__ bv,
        float* __restrict__ qT, float* __restrict__ kT, float* __restrict__ vT, int l) {
    const int z = blockIdx.z;
    const unsigned short* Wt = wt + (size_t)(z * 8 + l) * DD;
    const float* bias = (z == 0) ? bq : (z == 1) ? bk : bv;
    float* out = (z == 0) ? qT : (z == 1) ? kT : vT;

    __shared__ unsigned short As[64][40];
    __shared__ unsigned short Bs[64][40];
    const int t = threadIdx.x, lane = t & 63, w = t >> 6;
    const int m0 = blockIdx.y * 64, n0 = blockIdx.x * 64;

    f32x4 zero; zero[0] = zero[1] = zero[2] = zero[3] = 0.f;
    f32x4 acc[4];
    #pragma unroll
    for (int nt = 0; nt < 4; nt++) acc[nt] = zero;

    const int sr = t >> 2, sc = (t & 3) * 8;   // full 64x32 tile: 256 thr x 8 ushorts
    for (int kt = 0; kt < 512; kt += 32) {
        *(int4*)&As[sr][sc] = *(const int4*)&xb[(size_t)(m0 + sr) * 512 + kt + sc];
        *(int4*)&Bs[sr][sc] = *(const int4*)&Wt[(size_t)(n0 + sr) * 512 + kt + sc];
        __syncthreads();
        bf16x8 a = *(const bf16x8*)&As[w * 16 + (lane & 15)][(lane >> 4) * 8];
        #pragma unroll
        for (int nt = 0; nt < 4; nt++) {
            bf16x8 bb = *(const bf16x8*)&Bs[nt * 16 + (lane & 15)][(lane >> 4) * 8];
            acc[nt] = __builtin_amdgcn_mfma_f32_16x16x32_bf16(a, bb, acc[nt], 0, 0, 0);
        }
        __syncthreads();
    }
    #pragma unroll
    for (int nt = 0; nt < 4; nt++)
        #pragma unroll
        for (int reg = 0; reg < 4; reg++) {
            int row = m0 + w * 16 + (lane >> 4) * 4 + reg;
            int col = n0 + nt * 16 + (lane & 15);
            int b = row / S, i = row - b * S;
            int h = col >> 6, d = col & 63;
            out[(((size_t)b * H + h) * S + i) * HD + d] = acc[nt][reg] + bias[col];
        }
}

// ---------------- generic bf16 MFMA GEMM: C = A@Wt^T + bias ----------------
// MODE 1: relu -> Cf ; MODE 2: + resid -> Cf and bf16 Cb
template <int MODE>
__global__ __launch_bounds__(256) void k_gemm_b(const unsigned short* __restrict__ Ab,
        const unsigned short* __restrict__ Wt, const float* __restrict__ bias,
        float* __restrict__ Cf, unsigned short* __restrict__ Cb,
        const float* __restrict__ resid, int N, int K) {
    __shared__ unsigned short As[64][40];
    __shared__ unsigned short Bs[64][40];
    const int t = threadIdx.x, lane = t & 63, w = t >> 6;
    const int m0 = blockIdx.y * 64, n0 = blockIdx.x * 64;

    f32x4 zero; zero[0] = zero[1] = zero[2] = zero[3] = 0.f;
    f32x4 acc[4];
    #pragma unroll
    for (int nt = 0; nt < 4; nt++) acc[nt] = zero;

    const int sr = t >> 2, sc = (t & 3) * 8;
    for (int kt = 0; kt < K; kt += 32) {
        *(int4*)&As[sr][sc] = *(const int4*)&Ab[(size_t)(m0 + sr) * K + kt + sc];
        *(int4*)&Bs[sr][sc] = *(const int4*)&Wt[(size_t)(n0 + sr) * K + kt + sc];
        __syncthreads();
        bf16x8 a = *(const bf16x8*)&As[w * 16 + (lane & 15)][(lane >> 4) * 8];
        #pragma unroll
        for (int nt = 0; nt < 4; nt++) {
            bf16x8 bb = *(const bf16x8*)&Bs[nt * 16 + (lane & 15)][(lane >> 4) * 8];
            acc[nt] = __builtin_amdgcn_mfma_f32_16x16x32_bf16(a, bb, acc[nt], 0, 0, 0);
        }
        __syncthreads();
    }
    #pragma unroll
    for (int nt = 0; nt < 4; nt++)
        #pragma unroll
        for (int reg = 0; reg < 4; reg++) {
            int row = m0 + w * 16 + (lane >> 4) * 4 + reg;
            int col = n0 + nt * 16 + (lane & 15);
            float v = acc[nt][reg] + bias[col];
            if (MODE == 1) v = fmaxf(v, 0.f);
            if (MODE == 2) v += resid[(size_t)row * N + col];
            Cf[(size_t)row * N + col] = v;
            if (MODE == 2) Cb[(size_t)row * N + col] = f2b(v);
        }
}

// ---------------- fused attention (f32), bf16 bias in, bf16 ao out ----------------
__global__ __launch_bounds__(256) void k_attn(const float* __restrict__ qT,
        const float* __restrict__ kT, const float* __restrict__ vT,
        const unsigned short* __restrict__ biasL, unsigned short* __restrict__ aob) {
    __shared__ float qs[16][64];
    __shared__ float ks[64][68];
    __shared__ float sc[16][392];
    const int t = threadIdx.x;
    const int i0 = blockIdx.x * 16;
    const int h = blockIdx.y, b = blockIdx.z;
    const size_t baseQ = ((size_t)b * H + h) * S * HD;
    const float* qb = qT + baseQ;
    const float* kb = kT + baseQ;
    const float* vb = vT + baseQ;
    const unsigned short* bb = biasL + ((size_t)b * H + h) * SS + (size_t)i0 * S;

    #pragma unroll
    for (int m = 0; m < 4; m++) {
        int f = t + m * 256;
        qs[f >> 6][f & 63] = qb[(size_t)(i0 + (f >> 6)) * HD + (f & 63)];
    }
    const int i = t >> 4;
    const int j4 = (t & 15) * 4;

    for (int jt = 0; jt < S; jt += 64) {
        #pragma unroll
        for (int m = 0; m < 16; m++) {
            int f = t + m * 256;
            ks[f >> 6][f & 63] = kb[(size_t)(jt + (f >> 6)) * HD + (f & 63)];
        }
        __syncthreads();
        float s0 = 0.f, s1 = 0.f, s2 = 0.f, s3 = 0.f;
        #pragma unroll
        for (int d4 = 0; d4 < 64; d4 += 4) {
            float4 qv = *(const float4*)&qs[i][d4];
            float4 k0 = *(const float4*)&ks[j4 + 0][d4];
            float4 k1 = *(const float4*)&ks[j4 + 1][d4];
            float4 k2 = *(const float4*)&ks[j4 + 2][d4];
            float4 k3 = *(const float4*)&ks[j4 + 3][d4];
            s0 += qv.x * k0.x + qv.y * k0.y + qv.z * k0.z + qv.w * k0.w;
            s1 += qv.x * k1.x + qv.y * k1.y + qv.z * k1.z + qv.w * k1.w;
            s2 += qv.x * k2.x + qv.y * k2.y + qv.z * k2.z + qv.w * k2.w;
            s3 += qv.x * k3.x + qv.y * k3.y + qv.z * k3.z + qv.w * k3.w;
        }
        const unsigned short* bp = bb + (size_t)i * S + jt + j4;
        sc[i][jt + j4 + 0] = s0 * 0.125f + b2f(bp[0]);
        sc[i][jt + j4 + 1] = s1 * 0.125f + b2f(bp[1]);
        sc[i][jt + j4 + 2] = s2 * 0.125f + b2f(bp[2]);
        sc[i][jt + j4 + 3] = s3 * 0.125f + b2f(bp[3]);
        __syncthreads();
    }

    const int sub = t & 15;
    float mx = -1e30f;
    for (int j = sub; j < S; j += 16) mx = fmaxf(mx, sc[i][j]);
    #pragma unroll
    for (int m = 1; m < 16; m <<= 1) mx = fmaxf(mx, __shfl_xor(mx, m));
    float sum = 0.f;
    for (int j = sub; j < S; j += 16) {
        float p = __expf(sc[i][j] - mx);
        sc[i][j] = p;
        sum += p;
    }
    #pragma unroll
    for (int m = 1; m < 16; m <<= 1) sum += __shfl_xor(sum, m);
    const float inv = 1.f / sum;
    for (int j = sub; j < S; j += 16) sc[i][j] *= inv;
    __syncthreads();

    const int d4 = (t & 15) * 4;
    float o0 = 0.f, o1 = 0.f, o2 = 0.f, o3 = 0.f;
    for (int jt = 0; jt < S; jt += 64) {
        #pragma unroll
        for (int m = 0; m < 16; m++) {
            int f = t + m * 256;
            ks[f >> 6][f & 63] = vb[(size_t)(jt + (f >> 6)) * HD + (f & 63)];
        }
        __syncthreads();
        #pragma unroll 8
        for (int jj = 0; jj < 64; jj++) {
            float a = sc[i][jt + jj];
            float4 vv = *(const float4*)&ks[jj][d4];
            o0 += a * vv.x; o1 += a * vv.y; o2 += a * vv.z; o3 += a * vv.w;
        }
        __syncthreads();
    }
    ushort4 ov;
    ov.x = f2b(o0); ov.y = f2b(o1); ov.z = f2b(o2); ov.w = f2b(o3);
    *(ushort4*)&aob[((size_t)(b * S + i0 + i)) * D + h * HD + d4] = ov;
}

// ---------------- coords update ----------------
__global__ __launch_bounds__(256) void k_upd(const float* __restrict__ h1,
        const float* __restrict__ Wb2, const float* __restrict__ bb2,
        float* __restrict__ coords) {
    const int wv = threadIdx.x >> 6, lane = threadIdx.x & 63;
    const int row = blockIdx.x * 4 + wv;
    const float* hr = h1 + (size_t)row * D;
    float p0 = 0.f, p1 = 0.f, p2 = 0.f;
    #pragma unroll
    for (int m = 0; m < 8; m++) {
        int d = m * 64 + lane;
        float hv = hr[d];
        const float* w = Wb2 + (size_t)d * 6;
        p0 += hv * w[0]; p1 += hv * w[1]; p2 += hv * w[2];
    }
    #pragma unroll
    for (int m = 32; m; m >>= 1) {
        p0 += __shfl_xor(p0, m);
        p1 += __shfl_xor(p1, m);
        p2 += __shfl_xor(p2, m);
    }
    if (lane == 0) {
        coords[row * 3 + 0] += p0 + bb2[0];
        coords[row * 3 + 1] += p1 + bb2[1];
        coords[row * 3 + 2] += p2 + bb2[2];
    }
}

// ---------------- confidence + final output assembly ----------------
__global__ __launch_bounds__(256) void k_conf(const float* __restrict__ hc,
        const float* __restrict__ Wc2, const float* __restrict__ bc2,
        const float* __restrict__ coords, float* __restrict__ out) {
    const int wv = threadIdx.x >> 6, lane = threadIdx.x & 63;
    const int row = blockIdx.x * 4 + wv;
    const float* hr = hc + (size_t)row * 256;
    float p = 0.f;
    #pragma unroll
    for (int m = 0; m < 4; m++) p += hr[m * 64 + lane] * Wc2[m * 64 + lane];
    #pragma unroll
    for (int m = 32; m; m >>= 1) p += __shfl_xor(p, m);
    if (lane == 0) out[B * S * 3 + row] = 1.f / (1.f + __expf(-(p + bc2[0])));
    int ci = blockIdx.x * 12 + threadIdx.x;
    if (threadIdx.x < 12) out[ci] = coords[ci];
}

extern "C" void kernel_launch(void* const* d_in, const int* in_sizes, int n_in,
                              void* d_out, int out_size, void* d_ws, size_t ws_size,
                              hipStream_t stream) {
    const float* msa = (const float*)d_in[0];
    const float* pair = (const float*)d_in[1];
    const float* Wq = (const float*)d_in[2];
    const float* bq = (const float*)d_in[3];
    const float* Wk = (const float*)d_in[4];
    const float* bk = (const float*)d_in[5];
    const float* Wv = (const float*)d_in[6];
    const float* bv = (const float*)d_in[7];
    const float* Wpb = (const float*)d_in[8];
    const float* bpb = (const float*)d_in[9];
    const float* Wo = (const float*)d_in[10];
    const float* bo = (const float*)d_in[11];
    const float* Wb1 = (const float*)d_in[12];
    const float* bb1 = (const float*)d_in[13];
    const float* Wb2 = (const float*)d_in[14];
    const float* bb2 = (const float*)d_in[15];
    const float* Wc1 = (const float*)d_in[16];
    const float* bc1 = (const float*)d_in[17];
    const float* Wc2 = (const float*)d_in[18];
    const float* bc2 = (const float*)d_in[19];

    char* base = (char*)d_ws;
    float* x  = (float*)base;            base += (size_t)XN * 4;
    float* h1 = (float*)base;            base += (size_t)XN * 4;
    float* hc = (float*)base;            base += (size_t)BS * 256 * 4;
    float* qT = (float*)base;            base += (size_t)XN * 4;
    float* kT = (float*)base;            base += (size_t)XN * 4;
    float* vT = (float*)base;            base += (size_t)XN * 4;
    float* coords = (float*)base;        base += 16384;
    unsigned short* xb  = (unsigned short*)base;  base += (size_t)XN * 2;
    unsigned short* aob = (unsigned short*)base;  base += (size_t)XN * 2;
    unsigned short* wt  = (unsigned short*)base;  base += (size_t)34 * DD * 2;
    unsigned short* biasb = (unsigned short*)base;

    k_prep<<<dim3(8, 8, 34), 256, 0, stream>>>(Wq, Wk, Wv, Wo, Wb1, Wc1, wt);
    k_init<<<dim3((XN + 255) / 256), 256, 0, stream>>>(msa, x, xb, coords);
    k_biasm<<<dim3(S, B), 256, 0, stream>>>(pair, Wpb, bpb, biasb);

    for (int l = 0; l < L; ++l) {
        k_qkvm<<<dim3(8, 12, 3), 256, 0, stream>>>(xb, wt,
            bq + l * D, bk + l * D, bv + l * D, qT, kT, vT, l);
        k_attn<<<dim3(S / 16, H, B), 256, 0, stream>>>(qT, kT, vT,
            biasb + (size_t)l * BHSS, aob);
        k_gemm_b<2><<<dim3(8, 12), 256, 0, stream>>>(aob, wt + (size_t)(24 + l) * DD,
            bo + l * D, x, xb, x, D, D);
        k_gemm_b<1><<<dim3(8, 12), 256, 0, stream>>>(xb, wt + (size_t)32 * DD,
            bb1, h1, nullptr, nullptr, D, D);
        k_upd<<<BS / 4, 256, 0, stream>>>(h1, Wb2, bb2, coords);
    }

    k_gemm_b<1><<<dim3(4, 12), 256, 0, stream>>>(xb, wt + (size_t)33 * DD,
        bc1, hc, nullptr, nullptr, 256, D);
    k_conf<<<BS / 4, 256, 0, stream>>>(hc, Wc2, bc2, coords, (float*)d_out);
}

// Round 4
// 765.436 us; speedup vs baseline: 2.1744x; 1.1847x over previous
//
#include <hip/hip_runtime.h>
#include <math.h>

#define L 8
#define D 512
#define DD (D*D)
#define P 128
#define H 8
#define HD 64
#define B 2
#define NS 4
#define S 384
#define BS (B*S)                     // 768
#define XN (BS*D)                    // 393216
#define SS ((size_t)S*S)             // 147456
#define BHSS ((size_t)B*H*S*S)       // 2359296

typedef short bf16x8 __attribute__((ext_vector_type(8)));
typedef float f32x4 __attribute__((ext_vector_type(4)));

__device__ __forceinline__ unsigned short f2b(float f) {
    unsigned u = __float_as_uint(f);
    unsigned r = (u + 0x7FFF + ((u >> 16) & 1)) >> 16;
    return (unsigned short)r;
}
__device__ __forceinline__ float b2f(unsigned short u) {
    return __uint_as_float(((unsigned)u) << 16);
}

// ---------------- init: x = msa[:,0] (f32 + bf16), coords = 0 ----------------
__global__ __launch_bounds__(256) void k_init(const float* __restrict__ msa,
                                              float* __restrict__ x,
                                              unsigned short* __restrict__ xb,
                                              float* __restrict__ coords) {
    int idx = blockIdx.x * 256 + threadIdx.x;
    if (idx < XN) {
        int b = idx / (S * D);
        int rem = idx - b * (S * D);
        float v = msa[(size_t)b * NS * S * D + rem];
        x[idx] = v;
        xb[idx] = f2b(v);
    }
    if (idx < B * S * 3) coords[idx] = 0.f;
}

// ---------------- weight prep: transpose+convert to bf16 [N][K] ----------------
// z: 0-7 Wq[l], 8-15 Wk, 16-23 Wv, 24-31 Wo, 32 Wb1, 33 Wc1 (N=256)
__global__ __launch_bounds__(256) void k_prep(const float* __restrict__ Wq,
        const float* __restrict__ Wk, const float* __restrict__ Wv,
        const float* __restrict__ Wo, const float* __restrict__ Wb1,
        const float* __restrict__ Wc1, unsigned short* __restrict__ wt) {
    __shared__ float ts[64][65];
    const int z = blockIdx.z;
    const float* src; int N = 512;
    if (z < 8)       src = Wq + (size_t)z * DD;
    else if (z < 16) src = Wk + (size_t)(z - 8) * DD;
    else if (z < 24) src = Wv + (size_t)(z - 16) * DD;
    else if (z < 32) src = Wo + (size_t)(z - 24) * DD;
    else if (z == 32) src = Wb1;
    else { src = Wc1; N = 256; }
    unsigned short* dst = wt + (size_t)z * DD;

    const int n0 = blockIdx.x * 64, k0 = blockIdx.y * 64;
    if (n0 >= N) return;
    const int t = threadIdx.x;
    #pragma unroll
    for (int m = 0; m < 16; m++) {
        int f = t + m * 256;
        int r = f >> 6, c = f & 63;
        ts[r][c] = src[(size_t)(k0 + r) * N + n0 + c];
    }
    __syncthreads();
    #pragma unroll
    for (int m = 0; m < 4; m++) {
        int o4 = t + m * 256;
        int nr = o4 >> 4, k4 = o4 & 15;
        ushort4 pk;
        pk.x = f2b(ts[k4 * 4 + 0][nr]);
        pk.y = f2b(ts[k4 * 4 + 1][nr]);
        pk.z = f2b(ts[k4 * 4 + 2][nr]);
        pk.w = f2b(ts[k4 * 4 + 3][nr]);
        *(ushort4*)&dst[(size_t)(n0 + nr) * 512 + k0 + k4 * 4] = pk;
    }
}

// ---------------- pair bias via MFMA: bias[l,b,h,i,j] (bf16 out) ----------------
// block = (jt, i, b): one 64-j tile, all 64 (l,h). A = W'[lh][k], B = pair[j][k]
__global__ __launch_bounds__(256) void k_biasm(const float* __restrict__ pair,
        const float* __restrict__ Wpb, const float* __restrict__ bpb,
        unsigned short* __restrict__ bias) {
    __shared__ unsigned short Ws[64][136];   // [lh][k]
    __shared__ unsigned short Ps[64][136];   // [j][k]
    const int t = threadIdx.x;
    const int lane = t & 63, w = t >> 6;
    const int jt = blockIdx.x, i = blockIdx.y, b = blockIdx.z;

    // Wpb [l][p][h] f32 -> Ws[lh][k] bf16 (float4 loads, 4-row scatter)
    #pragma unroll
    for (int m = 0; m < 8; m++) {
        int f = (t + m * 256) * 4;            // 8192 floats total
        float4 wv = *(const float4*)&Wpb[f];
        int l = f >> 10, rem = f & 1023;
        int k = rem >> 3, h = rem & 7;        // h in {0,4}
        int lh = (l << 3) | h;
        Ws[lh + 0][k] = f2b(wv.x);
        Ws[lh + 1][k] = f2b(wv.y);
        Ws[lh + 2][k] = f2b(wv.z);
        Ws[lh + 3][k] = f2b(wv.w);
    }
    // pair tile [64 j][128 p] f32 -> Ps bf16 (float4 loads)
    const float* prow = pair + (((size_t)b * S + i) * S + jt * 64) * P;
    #pragma unroll
    for (int m = 0; m < 8; m++) {
        int f = (t + m * 256) * 4;            // 8192 floats total
        int r = f >> 7, c = f & 127;
        float4 pv = *(const float4*)&prow[f];
        ushort4 u;
        u.x = f2b(pv.x); u.y = f2b(pv.y); u.z = f2b(pv.z); u.w = f2b(pv.w);
        *(ushort4*)&Ps[r][c] = u;
    }
    __syncthreads();

    f32x4 acc[4];
    #pragma unroll
    for (int mi = 0; mi < 4; mi++) { acc[mi][0] = 0.f; acc[mi][1] = 0.f; acc[mi][2] = 0.f; acc[mi][3] = 0.f; }
    #pragma unroll
    for (int ks = 0; ks < 4; ks++) {
        bf16x8 bv = *(const bf16x8*)&Ps[w * 16 + (lane & 15)][ks * 32 + (lane >> 4) * 8];
        #pragma unroll
        for (int mi = 0; mi < 4; mi++) {
            bf16x8 av = *(const bf16x8*)&Ws[mi * 16 + (lane & 15)][ks * 32 + (lane >> 4) * 8];
            acc[mi] = __builtin_amdgcn_mfma_f32_16x16x32_bf16(av, bv, acc[mi], 0, 0, 0);
        }
    }
    const int j = jt * 64 + w * 16 + (lane & 15);
    #pragma unroll
    for (int mi = 0; mi < 4; mi++)
        #pragma unroll
        for (int reg = 0; reg < 4; reg++) {
            int lh = mi * 16 + (lane >> 4) * 4 + reg;
            float v = acc[mi][reg] + bpb[lh];
            size_t plane = ((size_t)(lh >> 3) * B + b) * H + (lh & 7);
            bias[plane * SS + (size_t)i * S + j] = f2b(v);
        }
}

// ---------------- QKV MFMA GEMM (K-pipelined), outputs f32 (B,H,S,HD) ----------------
__global__ __launch_bounds__(256) void k_qkvm(const unsigned short* __restrict__ xb,
        const unsigned short* __restrict__ wt,
        const float* __restrict__ bq, const float* __restrict__ bk, const float* __restrict__ bv,
        float* __restrict__ qT, float* __restrict__ kT, float* __restrict__ vT, int l) {
    const int z = blockIdx.z;
    const unsigned short* Wt = wt + (size_t)(z * 8 + l) * DD;
    const float* bias = (z == 0) ? bq : (z == 1) ? bk : bv;
    float* out = (z == 0) ? qT : (z == 1) ? kT : vT;

    __shared__ unsigned short As[64][40];
    __shared__ unsigned short Bs[64][40];
    const int t = threadIdx.x, lane = t & 63, w = t >> 6;
    const int m0 = blockIdx.y * 64, n0 = blockIdx.x * 64;

    f32x4 acc[4];
    #pragma unroll
    for (int nt = 0; nt < 4; nt++) { acc[nt][0] = 0.f; acc[nt][1] = 0.f; acc[nt][2] = 0.f; acc[nt][3] = 0.f; }

    const int sr = t >> 2, sc = (t & 3) * 8;   // full 64x32 tile: 256 thr x 8 ushorts
    const unsigned short* pa = &xb[(size_t)(m0 + sr) * 512 + sc];
    const unsigned short* pb = &Wt[(size_t)(n0 + sr) * 512 + sc];
    int4 ra = *(const int4*)pa;
    int4 rb = *(const int4*)pb;
    for (int kt = 0; kt < 512; kt += 32) {
        *(int4*)&As[sr][sc] = ra;
        *(int4*)&Bs[sr][sc] = rb;
        __syncthreads();
        if (kt + 32 < 512) {                  // prefetch next K-tile
            ra = *(const int4*)(pa + kt + 32);
            rb = *(const int4*)(pb + kt + 32);
        }
        bf16x8 a = *(const bf16x8*)&As[w * 16 + (lane & 15)][(lane >> 4) * 8];
        #pragma unroll
        for (int nt = 0; nt < 4; nt++) {
            bf16x8 bb = *(const bf16x8*)&Bs[nt * 16 + (lane & 15)][(lane >> 4) * 8];
            acc[nt] = __builtin_amdgcn_mfma_f32_16x16x32_bf16(a, bb, acc[nt], 0, 0, 0);
        }
        __syncthreads();
    }
    #pragma unroll
    for (int nt = 0; nt < 4; nt++)
        #pragma unroll
        for (int reg = 0; reg < 4; reg++) {
            int row = m0 + w * 16 + (lane >> 4) * 4 + reg;
            int col = n0 + nt * 16 + (lane & 15);
            int b = row / S, i = row - b * S;
            int h = col >> 6, d = col & 63;
            out[(((size_t)b * H + h) * S + i) * HD + d] = acc[nt][reg] + bias[col];
        }
}

// ---------------- generic bf16 MFMA GEMM (K-pipelined): C = A@Wt^T + bias ----------------
// MODE 1: relu -> Cf ; MODE 2: + resid -> Cf and bf16 Cb
template <int MODE>
__global__ __launch_bounds__(256) void k_gemm_b(const unsigned short* __restrict__ Ab,
        const unsigned short* __restrict__ Wt, const float* __restrict__ bias,
        float* __restrict__ Cf, unsigned short* __restrict__ Cb,
        const float* __restrict__ resid, int N, int K) {
    __shared__ unsigned short As[64][40];
    __shared__ unsigned short Bs[64][40];
    const int t = threadIdx.x, lane = t & 63, w = t >> 6;
    const int m0 = blockIdx.y * 64, n0 = blockIdx.x * 64;

    f32x4 acc[4];
    #pragma unroll
    for (int nt = 0; nt < 4; nt++) { acc[nt][0] = 0.f; acc[nt][1] = 0.f; acc[nt][2] = 0.f; acc[nt][3] = 0.f; }

    const int sr = t >> 2, sc = (t & 3) * 8;
    const unsigned short* pa = &Ab[(size_t)(m0 + sr) * K + sc];
    const unsigned short* pb = &Wt[(size_t)(n0 + sr) * K + sc];
    int4 ra = *(const int4*)pa;
    int4 rb = *(const int4*)pb;
    for (int kt = 0; kt < K; kt += 32) {
        *(int4*)&As[sr][sc] = ra;
        *(int4*)&Bs[sr][sc] = rb;
        __syncthreads();
        if (kt + 32 < K) {
            ra = *(const int4*)(pa + kt + 32);
            rb = *(const int4*)(pb + kt + 32);
        }
        bf16x8 a = *(const bf16x8*)&As[w * 16 + (lane & 15)][(lane >> 4) * 8];
        #pragma unroll
        for (int nt = 0; nt < 4; nt++) {
            bf16x8 bb = *(const bf16x8*)&Bs[nt * 16 + (lane & 15)][(lane >> 4) * 8];
            acc[nt] = __builtin_amdgcn_mfma_f32_16x16x32_bf16(a, bb, acc[nt], 0, 0, 0);
        }
        __syncthreads();
    }
    #pragma unroll
    for (int nt = 0; nt < 4; nt++)
        #pragma unroll
        for (int reg = 0; reg < 4; reg++) {
            int row = m0 + w * 16 + (lane >> 4) * 4 + reg;
            int col = n0 + nt * 16 + (lane & 15);
            float v = acc[nt][reg] + bias[col];
            if (MODE == 1) v = fmaxf(v, 0.f);
            if (MODE == 2) v += resid[(size_t)row * N + col];
            Cf[(size_t)row * N + col] = v;
            if (MODE == 2) Cb[(size_t)row * N + col] = f2b(v);
        }
}

// ---------------- fused attention (f32), bf16 bias in, bf16 ao out ----------------
__global__ __launch_bounds__(256) void k_attn(const float* __restrict__ qT,
        const float* __restrict__ kT, const float* __restrict__ vT,
        const unsigned short* __restrict__ biasL, unsigned short* __restrict__ aob) {
    __shared__ float qs[16][64];
    __shared__ float ks[64][68];
    __shared__ float sc[16][392];
    const int t = threadIdx.x;
    const int i0 = blockIdx.x * 16;
    const int h = blockIdx.y, b = blockIdx.z;
    const size_t baseQ = ((size_t)b * H + h) * S * HD;
    const float* qb = qT + baseQ;
    const float* kb = kT + baseQ;
    const float* vb = vT + baseQ;
    const unsigned short* bb = biasL + ((size_t)b * H + h) * SS + (size_t)i0 * S;

    #pragma unroll
    for (int m = 0; m < 4; m++) {
        int f = t + m * 256;
        qs[f >> 6][f & 63] = qb[(size_t)(i0 + (f >> 6)) * HD + (f & 63)];
    }
    const int i = t >> 4;
    const int j4 = (t & 15) * 4;

    for (int jt = 0; jt < S; jt += 64) {
        #pragma unroll
        for (int m = 0; m < 16; m++) {
            int f = t + m * 256;
            ks[f >> 6][f & 63] = kb[(size_t)(jt + (f >> 6)) * HD + (f & 63)];
        }
        __syncthreads();
        float s0 = 0.f, s1 = 0.f, s2 = 0.f, s3 = 0.f;
        #pragma unroll
        for (int d4 = 0; d4 < 64; d4 += 4) {
            float4 qv = *(const float4*)&qs[i][d4];
            float4 k0 = *(const float4*)&ks[j4 + 0][d4];
            float4 k1 = *(const float4*)&ks[j4 + 1][d4];
            float4 k2 = *(const float4*)&ks[j4 + 2][d4];
            float4 k3 = *(const float4*)&ks[j4 + 3][d4];
            s0 += qv.x * k0.x + qv.y * k0.y + qv.z * k0.z + qv.w * k0.w;
            s1 += qv.x * k1.x + qv.y * k1.y + qv.z * k1.z + qv.w * k1.w;
            s2 += qv.x * k2.x + qv.y * k2.y + qv.z * k2.z + qv.w * k2.w;
            s3 += qv.x * k3.x + qv.y * k3.y + qv.z * k3.z + qv.w * k3.w;
        }
        const unsigned short* bp = bb + (size_t)i * S + jt + j4;
        sc[i][jt + j4 + 0] = s0 * 0.125f + b2f(bp[0]);
        sc[i][jt + j4 + 1] = s1 * 0.125f + b2f(bp[1]);
        sc[i][jt + j4 + 2] = s2 * 0.125f + b2f(bp[2]);
        sc[i][jt + j4 + 3] = s3 * 0.125f + b2f(bp[3]);
        __syncthreads();
    }

    const int sub = t & 15;
    float mx = -1e30f;
    for (int j = sub; j < S; j += 16) mx = fmaxf(mx, sc[i][j]);
    #pragma unroll
    for (int m = 1; m < 16; m <<= 1) mx = fmaxf(mx, __shfl_xor(mx, m));
    float sum = 0.f;
    for (int j = sub; j < S; j += 16) {
        float p = __expf(sc[i][j] - mx);
        sc[i][j] = p;
        sum += p;
    }
    #pragma unroll
    for (int m = 1; m < 16; m <<= 1) sum += __shfl_xor(sum, m);
    const float inv = 1.f / sum;
    for (int j = sub; j < S; j += 16) sc[i][j] *= inv;
    __syncthreads();

    const int d4 = (t & 15) * 4;
    float o0 = 0.f, o1 = 0.f, o2 = 0.f, o3 = 0.f;
    for (int jt = 0; jt < S; jt += 64) {
        #pragma unroll
        for (int m = 0; m < 16; m++) {
            int f = t + m * 256;
            ks[f >> 6][f & 63] = vb[(size_t)(jt + (f >> 6)) * HD + (f & 63)];
        }
        __syncthreads();
        #pragma unroll 8
        for (int jj = 0; jj < 64; jj++) {
            float a = sc[i][jt + jj];
            float4 vv = *(const float4*)&ks[jj][d4];
            o0 += a * vv.x; o1 += a * vv.y; o2 += a * vv.z; o3 += a * vv.w;
        }
        __syncthreads();
    }
    ushort4 ov;
    ov.x = f2b(o0); ov.y = f2b(o1); ov.z = f2b(o2); ov.w = f2b(o3);
    *(ushort4*)&aob[((size_t)(b * S + i0 + i)) * D + h * HD + d4] = ov;
}

// ---------------- coords update ----------------
__global__ __launch_bounds__(256) void k_upd(const float* __restrict__ h1,
        const float* __restrict__ Wb2, const float* __restrict__ bb2,
        float* __restrict__ coords) {
    const int wv = threadIdx.x >> 6, lane = threadIdx.x & 63;
    const int row = blockIdx.x * 4 + wv;
    const float* hr = h1 + (size_t)row * D;
    float p0 = 0.f, p1 = 0.f, p2 = 0.f;
    #pragma unroll
    for (int m = 0; m < 8; m++) {
        int d = m * 64 + lane;
        float hv = hr[d];
        const float* w = Wb2 + (size_t)d * 6;
        p0 += hv * w[0]; p1 += hv * w[1]; p2 += hv * w[2];
    }
    #pragma unroll
    for (int m = 32; m; m >>= 1) {
        p0 += __shfl_xor(p0, m);
        p1 += __shfl_xor(p1, m);
        p2 += __shfl_xor(p2, m);
    }
    if (lane == 0) {
        coords[row * 3 + 0] += p0 + bb2[0];
        coords[row * 3 + 1] += p1 + bb2[1];
        coords[row * 3 + 2] += p2 + bb2[2];
    }
}

// ---------------- confidence + final output assembly ----------------
__global__ __launch_bounds__(256) void k_conf(const float* __restrict__ hc,
        const float* __restrict__ Wc2, const float* __restrict__ bc2,
        const float* __restrict__ coords, float* __restrict__ out) {
    const int wv = threadIdx.x >> 6, lane = threadIdx.x & 63;
    const int row = blockIdx.x * 4 + wv;
    const float* hr = hc + (size_t)row * 256;
    float p = 0.f;
    #pragma unroll
    for (int m = 0; m < 4; m++) p += hr[m * 64 + lane] * Wc2[m * 64 + lane];
    #pragma unroll
    for (int m = 32; m; m >>= 1) p += __shfl_xor(p, m);
    if (lane == 0) out[B * S * 3 + row] = 1.f / (1.f + __expf(-(p + bc2[0])));
    int ci = blockIdx.x * 12 + threadIdx.x;
    if (threadIdx.x < 12) out[ci] = coords[ci];
}

extern "C" void kernel_launch(void* const* d_in, const int* in_sizes, int n_in,
                              void* d_out, int out_size, void* d_ws, size_t ws_size,
                              hipStream_t stream) {
    const float* msa = (const float*)d_in[0];
    const float* pair = (const float*)d_in[1];
    const float* Wq = (const float*)d_in[2];
    const float* bq = (const float*)d_in[3];
    const float* Wk = (const float*)d_in[4];
    const float* bk = (const float*)d_in[5];
    const float* Wv = (const float*)d_in[6];
    const float* bv = (const float*)d_in[7];
    const float* Wpb = (const float*)d_in[8];
    const float* bpb = (const float*)d_in[9];
    const float* Wo = (const float*)d_in[10];
    const float* bo = (const float*)d_in[11];
    const float* Wb1 = (const float*)d_in[12];
    const float* bb1 = (const float*)d_in[13];
    const float* Wb2 = (const float*)d_in[14];
    const float* bb2 = (const float*)d_in[15];
    const float* Wc1 = (const float*)d_in[16];
    const float* bc1 = (const float*)d_in[17];
    const float* Wc2 = (const float*)d_in[18];
    const float* bc2 = (const float*)d_in[19];

    char* base = (char*)d_ws;
    float* x  = (float*)base;            base += (size_t)XN * 4;
    float* h1 = (float*)base;            base += (size_t)XN * 4;
    float* hc = (float*)base;            base += (size_t)BS * 256 * 4;
    float* qT = (float*)base;            base += (size_t)XN * 4;
    float* kT = (float*)base;            base += (size_t)XN * 4;
    float* vT = (float*)base;            base += (size_t)XN * 4;
    float* coords = (float*)base;        base += 16384;
    unsigned short* xb  = (unsigned short*)base;  base += (size_t)XN * 2;
    unsigned short* aob = (unsigned short*)base;  base += (size_t)XN * 2;
    unsigned short* wt  = (unsigned short*)base;  base += (size_t)34 * DD * 2;
    unsigned short* biasb = (unsigned short*)base;

    k_prep<<<dim3(8, 8, 34), 256, 0, stream>>>(Wq, Wk, Wv, Wo, Wb1, Wc1, wt);
    k_init<<<dim3((XN + 255) / 256), 256, 0, stream>>>(msa, x, xb, coords);
    k_biasm<<<dim3(6, S, B), 256, 0, stream>>>(pair, Wpb, bpb, biasb);

    for (int l = 0; l < L; ++l) {
        k_qkvm<<<dim3(8, 12, 3), 256, 0, stream>>>(xb, wt,
            bq + l * D, bk + l * D, bv + l * D, qT, kT, vT, l);
        k_attn<<<dim3(S / 16, H, B), 256, 0, stream>>>(qT, kT, vT,
            biasb + (size_t)l * BHSS, aob);
        k_gemm_b<2><<<dim3(8, 12), 256, 0, stream>>>(aob, wt + (size_t)(24 + l) * DD,
            bo + l * D, x, xb, x, D, D);
        k_gemm_b<1><<<dim3(8, 12), 256, 0, stream>>>(xb, wt + (size_t)32 * DD,
            bb1, h1, nullptr, nullptr, D, D);
        k_upd<<<BS / 4, 256, 0, stream>>>(h1, Wb2, bb2, coords);
    }

    k_gemm_b<1><<<dim3(4, 12), 256, 0, stream>>>(xb, wt + (size_t)33 * DD,
        bc1, hc, nullptr, nullptr, 256, D);
    k_conf<<<BS / 4, 256, 0, stream>>>(hc, Wc2, bc2, coords, (float*)d_out);
}

// Round 5
// 365.491 us; speedup vs baseline: 4.5537x; 2.0943x over previous
//
#include <hip/hip_runtime.h>
#include <math.h>

#define L 8
#define D 512
#define DD (D*D)
#define P 128
#define H 8
#define HD 64
#define B 2
#define NS 4
#define S 384
#define BS (B*S)                     // 768
#define XN (BS*D)                    // 393216
#define SS ((size_t)S*S)             // 147456
#define BHSS ((size_t)B*H*S*S)       // 2359296

typedef short bf16x8 __attribute__((ext_vector_type(8)));
typedef float f32x4 __attribute__((ext_vector_type(4)));

__device__ __forceinline__ unsigned short f2b(float f) {
    unsigned u = __float_as_uint(f);
    unsigned r = (u + 0x7FFF + ((u >> 16) & 1)) >> 16;
    return (unsigned short)r;
}
__device__ __forceinline__ float b2f(unsigned short u) {
    return __uint_as_float(((unsigned)u) << 16);
}

// ---------------- init: x = msa[:,0] (f32 + bf16), part = 0 ----------------
__global__ __launch_bounds__(256) void k_init(const float* __restrict__ msa,
                                              float* __restrict__ x,
                                              unsigned short* __restrict__ xb,
                                              float* __restrict__ part) {
    int idx = blockIdx.x * 256 + threadIdx.x;
    if (idx < XN) {
        int b = idx / (S * D);
        int rem = idx - b * (S * D);
        float v = msa[(size_t)b * NS * S * D + rem];
        x[idx] = v;
        xb[idx] = f2b(v);
    }
    if (idx < 8 * BS * 3) part[idx] = 0.f;
}

// ---------------- weight prep: transpose+convert to bf16 [N][K] ----------------
// z: 0-7 Wq[l], 8-15 Wk, 16-23 Wv, 24-31 Wo, 32 Wb1, 33 Wc1 (N=256)
__global__ __launch_bounds__(256) void k_prep(const float* __restrict__ Wq,
        const float* __restrict__ Wk, const float* __restrict__ Wv,
        const float* __restrict__ Wo, const float* __restrict__ Wb1,
        const float* __restrict__ Wc1, unsigned short* __restrict__ wt) {
    __shared__ float ts[64][65];
    const int z = blockIdx.z;
    const float* src; int N = 512;
    if (z < 8)       src = Wq + (size_t)z * DD;
    else if (z < 16) src = Wk + (size_t)(z - 8) * DD;
    else if (z < 24) src = Wv + (size_t)(z - 16) * DD;
    else if (z < 32) src = Wo + (size_t)(z - 24) * DD;
    else if (z == 32) src = Wb1;
    else { src = Wc1; N = 256; }
    unsigned short* dst = wt + (size_t)z * DD;

    const int n0 = blockIdx.x * 64, k0 = blockIdx.y * 64;
    if (n0 >= N) return;
    const int t = threadIdx.x;
    #pragma unroll
    for (int m = 0; m < 16; m++) {
        int f = t + m * 256;
        int r = f >> 6, c = f & 63;
        ts[r][c] = src[(size_t)(k0 + r) * N + n0 + c];
    }
    __syncthreads();
    #pragma unroll
    for (int m = 0; m < 4; m++) {
        int o4 = t + m * 256;
        int nr = o4 >> 4, k4 = o4 & 15;
        ushort4 pk;
        pk.x = f2b(ts[k4 * 4 + 0][nr]);
        pk.y = f2b(ts[k4 * 4 + 1][nr]);
        pk.z = f2b(ts[k4 * 4 + 2][nr]);
        pk.w = f2b(ts[k4 * 4 + 3][nr]);
        *(ushort4*)&dst[(size_t)(n0 + nr) * 512 + k0 + k4 * 4] = pk;
    }
}

// ---------------- pair bias via MFMA: bias[l,b,h,i,j] (bf16 out) ----------------
__global__ __launch_bounds__(256) void k_biasm(const float* __restrict__ pair,
        const float* __restrict__ Wpb, const float* __restrict__ bpb,
        unsigned short* __restrict__ bias) {
    __shared__ unsigned short Ws[64][136];   // [lh][k]
    __shared__ unsigned short Ps[64][136];   // [j][k]
    const int t = threadIdx.x;
    const int lane = t & 63, w = t >> 6;
    const int jt = blockIdx.x, i = blockIdx.y, b = blockIdx.z;

    #pragma unroll
    for (int m = 0; m < 8; m++) {
        int f = (t + m * 256) * 4;
        float4 wv = *(const float4*)&Wpb[f];
        int l = f >> 10, rem = f & 1023;
        int k = rem >> 3, h = rem & 7;
        int lh = (l << 3) | h;
        Ws[lh + 0][k] = f2b(wv.x);
        Ws[lh + 1][k] = f2b(wv.y);
        Ws[lh + 2][k] = f2b(wv.z);
        Ws[lh + 3][k] = f2b(wv.w);
    }
    const float* prow = pair + (((size_t)b * S + i) * S + jt * 64) * P;
    #pragma unroll
    for (int m = 0; m < 8; m++) {
        int f = (t + m * 256) * 4;
        int r = f >> 7, c = f & 127;
        float4 pv = *(const float4*)&prow[f];
        ushort4 u;
        u.x = f2b(pv.x); u.y = f2b(pv.y); u.z = f2b(pv.z); u.w = f2b(pv.w);
        *(ushort4*)&Ps[r][c] = u;
    }
    __syncthreads();

    f32x4 acc[4];
    #pragma unroll
    for (int mi = 0; mi < 4; mi++) { acc[mi][0] = 0.f; acc[mi][1] = 0.f; acc[mi][2] = 0.f; acc[mi][3] = 0.f; }
    #pragma unroll
    for (int ks = 0; ks < 4; ks++) {
        bf16x8 bv = *(const bf16x8*)&Ps[w * 16 + (lane & 15)][ks * 32 + (lane >> 4) * 8];
        #pragma unroll
        for (int mi = 0; mi < 4; mi++) {
            bf16x8 av = *(const bf16x8*)&Ws[mi * 16 + (lane & 15)][ks * 32 + (lane >> 4) * 8];
            acc[mi] = __builtin_amdgcn_mfma_f32_16x16x32_bf16(av, bv, acc[mi], 0, 0, 0);
        }
    }
    const int j = jt * 64 + w * 16 + (lane & 15);
    #pragma unroll
    for (int mi = 0; mi < 4; mi++)
        #pragma unroll
        for (int reg = 0; reg < 4; reg++) {
            int lh = mi * 16 + (lane >> 4) * 4 + reg;
            float v = acc[mi][reg] + bpb[lh];
            size_t plane = ((size_t)(lh >> 3) * B + b) * H + (lh & 7);
            bias[plane * SS + (size_t)i * S + j] = f2b(v);
        }
}

// ---------------- QKV MFMA GEMM (K-pipelined), bf16 out; V transposed ----------------
// q,k: [b,h,i,d]; v: [b,h,d,i]
__global__ __launch_bounds__(256) void k_qkvm(const unsigned short* __restrict__ xb,
        const unsigned short* __restrict__ wt,
        const float* __restrict__ bq, const float* __restrict__ bk, const float* __restrict__ bv,
        unsigned short* __restrict__ qbb, unsigned short* __restrict__ kbb,
        unsigned short* __restrict__ vtb, int l) {
    const int z = blockIdx.z;
    const unsigned short* Wt = wt + (size_t)(z * 8 + l) * DD;
    const float* bias = (z == 0) ? bq : (z == 1) ? bk : bv;
    unsigned short* out = (z == 0) ? qbb : (z == 1) ? kbb : vtb;

    __shared__ unsigned short As[64][40];
    __shared__ unsigned short Bs[64][40];
    const int t = threadIdx.x, lane = t & 63, w = t >> 6;
    const int m0 = blockIdx.y * 64, n0 = blockIdx.x * 64;

    f32x4 acc[4];
    #pragma unroll
    for (int nt = 0; nt < 4; nt++) { acc[nt][0] = 0.f; acc[nt][1] = 0.f; acc[nt][2] = 0.f; acc[nt][3] = 0.f; }

    const int sr = t >> 2, scc = (t & 3) * 8;
    const unsigned short* pa = &xb[(size_t)(m0 + sr) * 512 + scc];
    const unsigned short* pb = &Wt[(size_t)(n0 + sr) * 512 + scc];
    int4 ra = *(const int4*)pa;
    int4 rb = *(const int4*)pb;
    for (int kt = 0; kt < 512; kt += 32) {
        *(int4*)&As[sr][scc] = ra;
        *(int4*)&Bs[sr][scc] = rb;
        __syncthreads();
        if (kt + 32 < 512) {
            ra = *(const int4*)(pa + kt + 32);
            rb = *(const int4*)(pb + kt + 32);
        }
        bf16x8 a = *(const bf16x8*)&As[w * 16 + (lane & 15)][(lane >> 4) * 8];
        #pragma unroll
        for (int nt = 0; nt < 4; nt++) {
            bf16x8 bb = *(const bf16x8*)&Bs[nt * 16 + (lane & 15)][(lane >> 4) * 8];
            acc[nt] = __builtin_amdgcn_mfma_f32_16x16x32_bf16(a, bb, acc[nt], 0, 0, 0);
        }
        __syncthreads();
    }
    #pragma unroll
    for (int nt = 0; nt < 4; nt++)
        #pragma unroll
        for (int reg = 0; reg < 4; reg++) {
            int row = m0 + w * 16 + (lane >> 4) * 4 + reg;
            int col = n0 + nt * 16 + (lane & 15);
            int b = row / S, i = row - b * S;
            int h = col >> 6, d = col & 63;
            float v = acc[nt][reg] + bias[col];
            if (z < 2) out[(((size_t)b * H + h) * S + i) * HD + d] = f2b(v);
            else       out[(((size_t)b * H + h) * HD + d) * S + i] = f2b(v);
        }
}

// ---------------- MFMA flash attention: bf16 in/out ----------------
// grid (S/16, H, B); Q-tile 16 rows, full j=384
__global__ __launch_bounds__(256) void k_attnm(const unsigned short* __restrict__ qb,
        const unsigned short* __restrict__ kb, const unsigned short* __restrict__ vt,
        const unsigned short* __restrict__ biasL, unsigned short* __restrict__ aob) {
    __shared__ unsigned short qs[16][72];
    __shared__ unsigned short ksh[64][72];
    __shared__ unsigned short vsh[64][72];
    __shared__ float scs[16][392];
    __shared__ unsigned short pbs[16][392];
    __shared__ float invs[16];

    const int t = threadIdx.x, lane = t & 63, w = t >> 6;
    const int i0 = blockIdx.x * 16;
    const int h = blockIdx.y, b = blockIdx.z;
    const size_t bh = (size_t)b * H + h;
    const unsigned short* qp = qb + (bh * S + i0) * HD;
    const unsigned short* kp = kb + bh * S * HD;
    const unsigned short* vp = vt + bh * HD * S;
    const unsigned short* bp = biasL + bh * SS + (size_t)i0 * S;

    // stage Q tile (16x64) and bias rows (16x384) into pbs
    if (t < 128) {
        int r = t >> 3, c = (t & 7) * 8;
        *(int4*)&qs[r][c] = *(const int4*)&qp[r * HD + c];
    }
    #pragma unroll
    for (int m = 0; m < 3; m++) {
        int f = t + m * 256;                  // 768 x int4
        int r = f / 48, c = (f % 48) * 8;
        *(int4*)&pbs[r][c] = *(const int4*)&bp[(size_t)r * S + c];
    }
    __syncthreads();

    bf16x8 qa0 = *(const bf16x8*)&qs[lane & 15][(lane >> 4) * 8];
    bf16x8 qa1 = *(const bf16x8*)&qs[lane & 15][32 + (lane >> 4) * 8];

    // ---- QK^T * scale + bias -> scs ----
    for (int jt = 0; jt < 6; jt++) {
        #pragma unroll
        for (int m = 0; m < 2; m++) {
            int g = t + m * 256;              // 512 x int4
            int r = g >> 3, c = (g & 7) * 8;
            *(int4*)&ksh[r][c] = *(const int4*)&kp[(size_t)(jt * 64 + r) * HD + c];
        }
        __syncthreads();
        f32x4 acc; acc[0] = 0.f; acc[1] = 0.f; acc[2] = 0.f; acc[3] = 0.f;
        bf16x8 kb0 = *(const bf16x8*)&ksh[w * 16 + (lane & 15)][(lane >> 4) * 8];
        bf16x8 kb1 = *(const bf16x8*)&ksh[w * 16 + (lane & 15)][32 + (lane >> 4) * 8];
        acc = __builtin_amdgcn_mfma_f32_16x16x32_bf16(qa0, kb0, acc, 0, 0, 0);
        acc = __builtin_amdgcn_mfma_f32_16x16x32_bf16(qa1, kb1, acc, 0, 0, 0);
        const int col = jt * 64 + w * 16 + (lane & 15);
        #pragma unroll
        for (int reg = 0; reg < 4; reg++) {
            int row = (lane >> 4) * 4 + reg;
            scs[row][col] = acc[reg] * 0.125f + b2f(pbs[row][col]);
        }
        __syncthreads();
    }

    // ---- softmax over j (16 threads per row); unnormalized bf16 P -> pbs ----
    const int i = t >> 4, sub = t & 15;
    float mx = -1e30f;
    #pragma unroll
    for (int m = 0; m < 24; m++) mx = fmaxf(mx, scs[i][sub + m * 16]);
    #pragma unroll
    for (int m = 1; m < 16; m <<= 1) mx = fmaxf(mx, __shfl_xor(mx, m));
    float pv_[24];
    float sum = 0.f;
    #pragma unroll
    for (int m = 0; m < 24; m++) {
        float p = __expf(scs[i][sub + m * 16] - mx);
        pv_[m] = p;
        sum += p;
    }
    #pragma unroll
    for (int m = 1; m < 16; m <<= 1) sum += __shfl_xor(sum, m);
    if (sub == 0) invs[i] = 1.f / sum;
    __syncthreads();                          // bias reads of pbs are long done
    #pragma unroll
    for (int m = 0; m < 24; m++) pbs[i][sub + m * 16] = f2b(pv_[m]);
    __syncthreads();

    // ---- PV: out[i][d] = sum_j P[i][j] * V[j][d], V staged as Vt[d][j] ----
    f32x4 oacc; oacc[0] = 0.f; oacc[1] = 0.f; oacc[2] = 0.f; oacc[3] = 0.f;
    for (int jt = 0; jt < 6; jt++) {
        #pragma unroll
        for (int m = 0; m < 2; m++) {
            int g = t + m * 256;
            int r = g >> 3, c = (g & 7) * 8;
            *(int4*)&vsh[r][c] = *(const int4*)&vp[(size_t)r * S + jt * 64 + c];
        }
        __syncthreads();
        #pragma unroll
        for (int kk = 0; kk < 2; kk++) {
            bf16x8 a = *(const bf16x8*)&pbs[lane & 15][jt * 64 + kk * 32 + (lane >> 4) * 8];
            bf16x8 bb = *(const bf16x8*)&vsh[w * 16 + (lane & 15)][kk * 32 + (lane >> 4) * 8];
            oacc = __builtin_amdgcn_mfma_f32_16x16x32_bf16(a, bb, oacc, 0, 0, 0);
        }
        __syncthreads();
    }
    #pragma unroll
    for (int reg = 0; reg < 4; reg++) {
        int row = (lane >> 4) * 4 + reg;
        int d = w * 16 + (lane & 15);
        float v = oacc[reg] * invs[row];
        aob[((size_t)(b * S + i0 + row)) * D + h * HD + d] = f2b(v);
    }
}

// ---------------- generic bf16 MFMA GEMM (K-pipelined): C = A@Wt^T + bias ----------------
// MODE 1: relu -> Cf ; MODE 2: +resid -> Cf and bf16 Cb ; MODE 3: relu, no store,
//   coords partial: part[nblk][row][c] += sum_cols relu(v)*Wb2[col][c]
template <int MODE>
__global__ __launch_bounds__(256) void k_gemm_b(const unsigned short* __restrict__ Ab,
        const unsigned short* __restrict__ Wt, const float* __restrict__ bias,
        float* __restrict__ Cf, unsigned short* __restrict__ Cb,
        const float* __restrict__ resid, const float* __restrict__ Wb2g,
        float* __restrict__ part, int N, int K) {
    __shared__ unsigned short As[64][40];
    __shared__ unsigned short Bs[64][40];
    const int t = threadIdx.x, lane = t & 63, w = t >> 6;
    const int m0 = blockIdx.y * 64, n0 = blockIdx.x * 64;

    f32x4 acc[4];
    #pragma unroll
    for (int nt = 0; nt < 4; nt++) { acc[nt][0] = 0.f; acc[nt][1] = 0.f; acc[nt][2] = 0.f; acc[nt][3] = 0.f; }

    const int sr = t >> 2, scc = (t & 3) * 8;
    const unsigned short* pa = &Ab[(size_t)(m0 + sr) * K + scc];
    const unsigned short* pb = &Wt[(size_t)(n0 + sr) * K + scc];
    int4 ra = *(const int4*)pa;
    int4 rb = *(const int4*)pb;
    for (int kt = 0; kt < K; kt += 32) {
        *(int4*)&As[sr][scc] = ra;
        *(int4*)&Bs[sr][scc] = rb;
        __syncthreads();
        if (kt + 32 < K) {
            ra = *(const int4*)(pa + kt + 32);
            rb = *(const int4*)(pb + kt + 32);
        }
        bf16x8 a = *(const bf16x8*)&As[w * 16 + (lane & 15)][(lane >> 4) * 8];
        #pragma unroll
        for (int nt = 0; nt < 4; nt++) {
            bf16x8 bb = *(const bf16x8*)&Bs[nt * 16 + (lane & 15)][(lane >> 4) * 8];
            acc[nt] = __builtin_amdgcn_mfma_f32_16x16x32_bf16(a, bb, acc[nt], 0, 0, 0);
        }
        __syncthreads();
    }

    if (MODE == 3) {
        float w2[4][3];
        #pragma unroll
        for (int nt = 0; nt < 4; nt++) {
            int col = n0 + nt * 16 + (lane & 15);
            w2[nt][0] = Wb2g[col * 6 + 0];
            w2[nt][1] = Wb2g[col * 6 + 1];
            w2[nt][2] = Wb2g[col * 6 + 2];
        }
        #pragma unroll
        for (int reg = 0; reg < 4; reg++) {
            float p0 = 0.f, p1 = 0.f, p2 = 0.f;
            #pragma unroll
            for (int nt = 0; nt < 4; nt++) {
                float v = fmaxf(acc[nt][reg] + bias[n0 + nt * 16 + (lane & 15)], 0.f);
                p0 += v * w2[nt][0];
                p1 += v * w2[nt][1];
                p2 += v * w2[nt][2];
            }
            #pragma unroll
            for (int m = 1; m < 16; m <<= 1) {
                p0 += __shfl_xor(p0, m);
                p1 += __shfl_xor(p1, m);
                p2 += __shfl_xor(p2, m);
            }
            if ((lane & 15) == 0) {
                int row = m0 + w * 16 + (lane >> 4) * 4 + reg;
                float* pp = &part[((size_t)blockIdx.x * BS + row) * 3];
                pp[0] += p0; pp[1] += p1; pp[2] += p2;
            }
        }
    } else {
        #pragma unroll
        for (int nt = 0; nt < 4; nt++)
            #pragma unroll
            for (int reg = 0; reg < 4; reg++) {
                int row = m0 + w * 16 + (lane >> 4) * 4 + reg;
                int col = n0 + nt * 16 + (lane & 15);
                float v = acc[nt][reg] + bias[col];
                if (MODE == 1) v = fmaxf(v, 0.f);
                if (MODE == 2) v += resid[(size_t)row * N + col];
                Cf[(size_t)row * N + col] = v;
                if (MODE == 2) Cb[(size_t)row * N + col] = f2b(v);
            }
    }
}

// ---------------- confidence + coords assembly ----------------
__global__ __launch_bounds__(256) void k_conf(const float* __restrict__ hc,
        const float* __restrict__ Wc2, const float* __restrict__ bc2,
        const float* __restrict__ part, const float* __restrict__ bb2,
        float* __restrict__ out) {
    const int wv = threadIdx.x >> 6, lane = threadIdx.x & 63;
    const int row = blockIdx.x * 4 + wv;
    const float* hr = hc + (size_t)row * 256;
    float p = 0.f;
    #pragma unroll
    for (int m = 0; m < 4; m++) p += hr[m * 64 + lane] * Wc2[m * 64 + lane];
    #pragma unroll
    for (int m = 32; m; m >>= 1) p += __shfl_xor(p, m);
    if (lane == 0) out[B * S * 3 + row] = 1.f / (1.f + __expf(-(p + bc2[0])));
    int ci = blockIdx.x * 12 + threadIdx.x;
    if (threadIdx.x < 12) {
        int r = ci / 3, c = ci - r * 3;
        float s = 8.f * bb2[c];
        #pragma unroll
        for (int nb = 0; nb < 8; nb++) s += part[((size_t)nb * BS + r) * 3 + c];
        out[ci] = s;
    }
}

extern "C" void kernel_launch(void* const* d_in, const int* in_sizes, int n_in,
                              void* d_out, int out_size, void* d_ws, size_t ws_size,
                              hipStream_t stream) {
    const float* msa = (const float*)d_in[0];
    const float* pair = (const float*)d_in[1];
    const float* Wq = (const float*)d_in[2];
    const float* bq = (const float*)d_in[3];
    const float* Wk = (const float*)d_in[4];
    const float* bk = (const float*)d_in[5];
    const float* Wv = (const float*)d_in[6];
    const float* bv = (const float*)d_in[7];
    const float* Wpb = (const float*)d_in[8];
    const float* bpb = (const float*)d_in[9];
    const float* Wo = (const float*)d_in[10];
    const float* bo = (const float*)d_in[11];
    const float* Wb1 = (const float*)d_in[12];
    const float* bb1 = (const float*)d_in[13];
    const float* Wb2 = (const float*)d_in[14];
    const float* bb2 = (const float*)d_in[15];
    const float* Wc1 = (const float*)d_in[16];
    const float* bc1 = (const float*)d_in[17];
    const float* Wc2 = (const float*)d_in[18];
    const float* bc2 = (const float*)d_in[19];

    char* base = (char*)d_ws;
    float* x    = (float*)base;            base += (size_t)XN * 4;
    float* hc   = (float*)base;            base += (size_t)BS * 256 * 4;
    float* part = (float*)base;            base += (size_t)8 * BS * 3 * 4;
    unsigned short* xb  = (unsigned short*)base;  base += (size_t)XN * 2;
    unsigned short* aob = (unsigned short*)base;  base += (size_t)XN * 2;
    unsigned short* qbb = (unsigned short*)base;  base += (size_t)XN * 2;
    unsigned short* kbb = (unsigned short*)base;  base += (size_t)XN * 2;
    unsigned short* vtb = (unsigned short*)base;  base += (size_t)XN * 2;
    unsigned short* wt  = (unsigned short*)base;  base += (size_t)34 * DD * 2;
    unsigned short* biasb = (unsigned short*)base;

    k_prep<<<dim3(8, 8, 34), 256, 0, stream>>>(Wq, Wk, Wv, Wo, Wb1, Wc1, wt);
    k_init<<<dim3((XN + 255) / 256), 256, 0, stream>>>(msa, x, xb, part);
    k_biasm<<<dim3(6, S, B), 256, 0, stream>>>(pair, Wpb, bpb, biasb);

    for (int l = 0; l < L; ++l) {
        k_qkvm<<<dim3(8, 12, 3), 256, 0, stream>>>(xb, wt,
            bq + l * D, bk + l * D, bv + l * D, qbb, kbb, vtb, l);
        k_attnm<<<dim3(S / 16, H, B), 256, 0, stream>>>(qbb, kbb, vtb,
            biasb + (size_t)l * BHSS, aob);
        k_gemm_b<2><<<dim3(8, 12), 256, 0, stream>>>(aob, wt + (size_t)(24 + l) * DD,
            bo + l * D, x, xb, x, nullptr, nullptr, D, D);
        k_gemm_b<3><<<dim3(8, 12), 256, 0, stream>>>(xb, wt + (size_t)32 * DD,
            bb1, nullptr, nullptr, nullptr, Wb2, part, D, D);
    }

    k_gemm_b<1><<<dim3(4, 12), 256, 0, stream>>>(xb, wt + (size_t)33 * DD,
        bc1, hc, nullptr, nullptr, nullptr, nullptr, 256, D);
    k_conf<<<BS / 4, 256, 0, stream>>>(hc, Wc2, bc2, part, bb2, (float*)d_out);
}